// Round 1
// baseline (691.378 us; speedup 1.0000x reference)
//
#include <hip/hip_runtime.h>

// Problem constants: B=4, S=2048, D=1024, H=16, DK=DV=64
typedef __attribute__((ext_vector_type(8))) short bf16x8;  // 8 bf16 = 4 VGPR
typedef __attribute__((ext_vector_type(4))) float f32x4;   // MFMA acc

__device__ __forceinline__ short f2bf(float x) {
  union { float f; unsigned u; } v; v.f = x;
  unsigned r = v.u + 0x7fffu + ((v.u >> 16) & 1u);  // RNE
  return (short)(r >> 16);
}

__device__ __forceinline__ void async16(const void* g, void* l) {
  __builtin_amdgcn_global_load_lds(
      (const __attribute__((address_space(1))) unsigned int*)g,
      (__attribute__((address_space(3))) unsigned int*)l, 16, 0, 0);
}

// Stage a 64x64 bf16 tile (8KB) into LDS [64 rows][128B], with read-swizzle
// byte ^ ((row&7)<<4). global_load_lds writes linearly (base + lane*16), so the
// swizzle is applied to the per-lane GLOBAL source address (guide §5 m173).
__device__ __forceinline__ void stage8k(const char* gbase, int rowStride, short* lds, int tid) {
  int wave = tid >> 6, lane = tid & 63;
#pragma unroll
  for (int j = 0; j < 2; ++j) {
    int chunk = wave * 128 + j * 64 + lane;   // 0..511 (16B chunks)
    int row = chunk >> 3;
    int colb = (chunk & 7) << 4;
    const char* src = gbase + row * rowStride + (colb ^ ((row & 7) << 4));
    char* dst = (char*)lds + (wave * 128 + j * 64) * 16;  // wave-uniform base
    async16(src, dst);
  }
}

// ---------------------------------------------------------------------------
// Weight convert+transpose: W[k][n] fp32 -> Wt[n][k] bf16, 4 matrices.
__global__ __launch_bounds__(256) void cvtw_k(const float* Wq, const float* Wk,
                                              const float* Wv, const float* Wo, short* Wt) {
  int t = blockIdx.x * 256 + threadIdx.x;   // 0 .. 1M-1, 4 elems each
  int mat = t >> 18;
  int rem = t & 262143;
  int row = rem >> 8;        // k
  int col4 = rem & 255;      // n/4
  const float* src = mat == 0 ? Wq : (mat == 1 ? Wk : (mat == 2 ? Wv : Wo));
  float4 v = *(const float4*)(src + (size_t)row * 1024 + col4 * 4);
  short* dstm = Wt + (size_t)mat * 1048576;
  int n = col4 * 4;
  dstm[(size_t)(n + 0) * 1024 + row] = f2bf(v.x);
  dstm[(size_t)(n + 1) * 1024 + row] = f2bf(v.y);
  dstm[(size_t)(n + 2) * 1024 + row] = f2bf(v.z);
  dstm[(size_t)(n + 3) * 1024 + row] = f2bf(v.w);
}

// ---------------------------------------------------------------------------
// GEMM: C = A(8192x1024) * W^T-stored(1024x1024) + bias.
// MODE 0: A = fp32 activations (z selects query/key/value), writes bf16
//         Q (scaled 1/8, (bh,s,d)), K ((bh,s,d)), V transposed ((bh,d,s)).
// MODE 1: A = bf16 attention weights, writes fp32 to d_out part 1.
// 128x128 tile, BK=32, 4 waves (2x2 of 64x64), double-buffered LDS with
// padded 80B rows (conflict-free ds_read_b128 fragments, no swizzle needed).
template <int MODE>
__global__ __launch_bounds__(256) void gemm_k(
    const float* Af0, const float* Af1, const float* Af2,
    const short* Ab, const short* Wt,
    const float* b0, const float* b1, const float* b2,
    short* Qp, short* Kp, short* Vpt, float* outF) {
  __shared__ short As[2][128 * 40];  // 80B rows: 32 data cols + 8 pad
  __shared__ short Bs[2][128 * 40];
  int tid = threadIdx.x;
  int lane = tid & 63, wave = tid >> 6;
  int g = lane >> 4, c = lane & 15;
  int n0 = blockIdx.x * 128, m0 = blockIdx.y * 128, z = blockIdx.z;

  const float* Af = nullptr;
  const float* bias;
  const short* Wz;
  if (MODE == 0) {
    Af = z == 0 ? Af0 : (z == 1 ? Af1 : Af2);
    bias = z == 0 ? b0 : (z == 1 ? b1 : b2);
    Wz = Wt + (size_t)z * 1048576;
  } else {
    bias = b0;
    Wz = Wt;
  }

  float4 arf[4];  // MODE0 A staging regs (fp32)
  int4 ari[2];    // MODE1 A staging regs (bf16 x8)
  int4 bri[2];    // B staging regs

  auto loadA = [&](int ks) {
    int kb = ks * 32;
    if (MODE == 0) {
#pragma unroll
      for (int i = 0; i < 4; ++i) {
        int cdx = i * 256 + tid;
        int row = cdx >> 3, col = (cdx & 7) << 2;
        arf[i] = *(const float4*)(Af + (size_t)(m0 + row) * 1024 + kb + col);
      }
    } else {
#pragma unroll
      for (int i = 0; i < 2; ++i) {
        int cdx = i * 256 + tid;
        int row = cdx >> 2, colb = (cdx & 3) << 4;
        ari[i] = *(const int4*)((const char*)Ab + ((size_t)(m0 + row) * 1024 + kb) * 2 + colb);
      }
    }
  };
  auto loadB = [&](int ks) {
    int kb = ks * 32;
#pragma unroll
    for (int i = 0; i < 2; ++i) {
      int cdx = i * 256 + tid;
      int row = cdx >> 2, colb = (cdx & 3) << 4;
      bri[i] = *(const int4*)((const char*)Wz + ((size_t)(n0 + row) * 1024 + kb) * 2 + colb);
    }
  };
  auto writeA = [&](int buf) {
    if (MODE == 0) {
#pragma unroll
      for (int i = 0; i < 4; ++i) {
        int cdx = i * 256 + tid;
        int row = cdx >> 3, col = (cdx & 7) << 2;
        short4 h;
        h.x = f2bf(arf[i].x); h.y = f2bf(arf[i].y);
        h.z = f2bf(arf[i].z); h.w = f2bf(arf[i].w);
        *(short4*)((char*)&As[buf][0] + row * 80 + col * 2) = h;
      }
    } else {
#pragma unroll
      for (int i = 0; i < 2; ++i) {
        int cdx = i * 256 + tid;
        int row = cdx >> 2, colb = (cdx & 3) << 4;
        *(int4*)((char*)&As[buf][0] + row * 80 + colb) = ari[i];
      }
    }
  };
  auto writeB = [&](int buf) {
#pragma unroll
    for (int i = 0; i < 2; ++i) {
      int cdx = i * 256 + tid;
      int row = cdx >> 2, colb = (cdx & 3) << 4;
      *(int4*)((char*)&Bs[buf][0] + row * 80 + colb) = bri[i];
    }
  };

  f32x4 acc[4][4];
#pragma unroll
  for (int i = 0; i < 4; ++i)
#pragma unroll
    for (int j = 0; j < 4; ++j) acc[i][j] = (f32x4){0.f, 0.f, 0.f, 0.f};

  int wr = (wave >> 1) * 64, wc = (wave & 1) * 64;

  loadA(0); loadB(0);
  writeA(0); writeB(0);
  int cur = 0;
  for (int ks = 0; ks < 32; ++ks) {
    __syncthreads();
    if (ks + 1 < 32) { loadA(ks + 1); loadB(ks + 1); }  // issue early (T14)
    bf16x8 af[4], bfv[4];
#pragma unroll
    for (int mt = 0; mt < 4; ++mt)
      af[mt] = *(const bf16x8*)((const char*)&As[cur][0] + (wr + mt * 16 + c) * 80 + g * 16);
#pragma unroll
    for (int nt = 0; nt < 4; ++nt)
      bfv[nt] = *(const bf16x8*)((const char*)&Bs[cur][0] + (wc + nt * 16 + c) * 80 + g * 16);
#pragma unroll
    for (int mt = 0; mt < 4; ++mt)
#pragma unroll
      for (int nt = 0; nt < 4; ++nt)
        acc[mt][nt] = __builtin_amdgcn_mfma_f32_16x16x32_bf16(af[mt], bfv[nt], acc[mt][nt], 0, 0, 0);
    if (ks + 1 < 32) { writeA(cur ^ 1); writeB(cur ^ 1); }  // write late
    cur ^= 1;
  }

#pragma unroll
  for (int nt = 0; nt < 4; ++nt) {
    int n = n0 + wc + nt * 16 + c;
    float bb = bias[n];
#pragma unroll
    for (int mt = 0; mt < 4; ++mt) {
#pragma unroll
      for (int r = 0; r < 4; ++r) {
        int m = m0 + wr + mt * 16 + g * 4 + r;
        float vv = acc[mt][nt][r] + bb;
        if (MODE == 0) {
          int bh = (m >> 11) * 16 + (n >> 6);
          if (z == 0) {
            Qp[((size_t)bh * 2048 + (m & 2047)) * 64 + (n & 63)] = f2bf(vv * 0.125f);
          } else if (z == 1) {
            Kp[((size_t)bh * 2048 + (m & 2047)) * 64 + (n & 63)] = f2bf(vv);
          } else {
            Vpt[((size_t)bh * 64 + (n & 63)) * 2048 + (m & 2047)] = f2bf(vv);
          }
        } else {
          outF[(size_t)m * 1024 + n] = vv;
        }
      }
    }
  }
}

// ---------------------------------------------------------------------------
// Flash attention: block = (64 q-rows, one bh). 4 waves x 16 rows.
// KV tiles of 64, double-buffered via global_load_lds (swizzled source).
__global__ __launch_bounds__(256) void attn_k(const short* Qp, const short* Kp,
                                              const short* Vpt, const float* mask,
                                              float* outW, short* wbf) {
  __shared__ short Qs[64 * 64];
  __shared__ short Ks[2][64 * 64];
  __shared__ short Vs[2][64 * 64];
  __shared__ short Ps[64 * 64];
  int tid = threadIdx.x, lane = tid & 63, wave = tid >> 6;
  int g = lane >> 4, c = lane & 15;
  int qt = blockIdx.x, bh = blockIdx.y;
  int b = bh >> 4, h = bh & 15;

  const char* Qg = (const char*)Qp + ((size_t)bh * 2048 + qt * 64) * 128;
  const char* Kg = (const char*)Kp + (size_t)bh * 2048 * 128;
  const char* Vg = (const char*)Vpt + (size_t)bh * 64 * 4096;

  stage8k(Qg, 128, Qs, tid);
  stage8k(Kg, 128, Ks[0], tid);
  stage8k(Vg, 4096, Vs[0], tid);

  f32x4 acco[4];
  float mrun[4], lrun[4];
#pragma unroll
  for (int i = 0; i < 4; ++i) {
    acco[i] = (f32x4){0.f, 0.f, 0.f, 0.f};
    mrun[i] = -1e30f; lrun[i] = 0.f;
  }

  __syncthreads();  // Q + tile0 staged (drains vmcnt)

  bf16x8 aq[2];
  {
    int row = wave * 16 + c;
#pragma unroll
    for (int k2 = 0; k2 < 2; ++k2)
      aq[k2] = *(const bf16x8*)((const char*)Qs + row * 128 +
                                ((k2 * 64 + g * 16) ^ ((row & 7) << 4)));
  }

  int cur = 0;
  for (int t = 0; t < 32; ++t) {
    if (t > 0) __syncthreads();
    if (t + 1 < 32) {
      stage8k(Kg + (size_t)(t + 1) * 8192, 128, Ks[cur ^ 1], tid);
      stage8k(Vg + (size_t)(t + 1) * 128, 4096, Vs[cur ^ 1], tid);
    }
    // ---- S = Q K^T (rows: this wave's 16 q rows; cols: 64 kv) ----
    f32x4 sc[4];
#pragma unroll
    for (int n = 0; n < 4; ++n) {
      sc[n] = (f32x4){0.f, 0.f, 0.f, 0.f};
#pragma unroll
      for (int k2 = 0; k2 < 2; ++k2) {
        int row = n * 16 + c;
        bf16x8 bk = *(const bf16x8*)((const char*)&Ks[cur][0] + row * 128 +
                                     ((k2 * 64 + g * 16) ^ ((row & 7) << 4)));
        sc[n] = __builtin_amdgcn_mfma_f32_16x16x32_bf16(aq[k2], bk, sc[n], 0, 0, 0);
      }
    }
    // ---- additive mask + online softmax (wave-parallel) ----
    float mk[4];
#pragma unroll
    for (int n = 0; n < 4; ++n) mk[n] = mask[(size_t)b * 2048 + t * 64 + n * 16 + c];
#pragma unroll
    for (int n = 0; n < 4; ++n)
#pragma unroll
      for (int r = 0; r < 4; ++r) sc[n][r] += mk[n];

    float fsc[4];
#pragma unroll
    for (int r = 0; r < 4; ++r) {
      float tm = fmaxf(fmaxf(sc[0][r], sc[1][r]), fmaxf(sc[2][r], sc[3][r]));
      tm = fmaxf(tm, __shfl_xor(tm, 1));
      tm = fmaxf(tm, __shfl_xor(tm, 2));
      tm = fmaxf(tm, __shfl_xor(tm, 4));
      tm = fmaxf(tm, __shfl_xor(tm, 8));
      float mnew = fmaxf(mrun[r], tm);
      fsc[r] = __expf(mrun[r] - mnew);
      mrun[r] = mnew;
    }
    float p[4][4], rs[4];
#pragma unroll
    for (int r = 0; r < 4; ++r) rs[r] = 0.f;
#pragma unroll
    for (int n = 0; n < 4; ++n)
#pragma unroll
      for (int r = 0; r < 4; ++r) { p[n][r] = __expf(sc[n][r] - mrun[r]); rs[r] += p[n][r]; }
#pragma unroll
    for (int r = 0; r < 4; ++r) {
      float s = rs[r];
      s += __shfl_xor(s, 1); s += __shfl_xor(s, 2);
      s += __shfl_xor(s, 4); s += __shfl_xor(s, 8);
      lrun[r] = lrun[r] * fsc[r] + s;
    }
#pragma unroll
    for (int n = 0; n < 4; ++n)
#pragma unroll
      for (int r = 0; r < 4; ++r) acco[n][r] *= fsc[r];
    // ---- P -> LDS (bf16, swizzled; wave-local rows, DS in-order per wave) ----
#pragma unroll
    for (int n = 0; n < 4; ++n)
#pragma unroll
      for (int r = 0; r < 4; ++r) {
        int row = wave * 16 + g * 4 + r;
        *(short*)((char*)Ps + row * 128 + ((n * 32 + c * 2) ^ ((row & 7) << 4))) = f2bf(p[n][r]);
      }
    // ---- O += P V ----
#pragma unroll
    for (int k2 = 0; k2 < 2; ++k2) {
      int row = wave * 16 + c;
      bf16x8 ap = *(const bf16x8*)((const char*)Ps + row * 128 +
                                   ((k2 * 64 + g * 16) ^ ((row & 7) << 4)));
#pragma unroll
      for (int n2 = 0; n2 < 4; ++n2) {
        int rv = n2 * 16 + c;
        bf16x8 bv = *(const bf16x8*)((const char*)&Vs[cur][0] + rv * 128 +
                                     ((k2 * 64 + g * 16) ^ ((rv & 7) << 4)));
        acco[n2] = __builtin_amdgcn_mfma_f32_16x16x32_bf16(ap, bv, acco[n2], 0, 0, 0);
      }
    }
    cur ^= 1;
  }
  // ---- epilogue: weights = O / l ----
#pragma unroll
  for (int n = 0; n < 4; ++n)
#pragma unroll
    for (int r = 0; r < 4; ++r) {
      int srow = qt * 64 + wave * 16 + g * 4 + r;
      int col = h * 64 + n * 16 + c;
      float v = acco[n][r] / lrun[r];
      size_t idx = ((size_t)b * 2048 + srow) * 1024 + col;
      outW[idx] = v;
      wbf[idx] = f2bf(v);
    }
}

// ---------------------------------------------------------------------------
extern "C" void kernel_launch(void* const* d_in, const int* in_sizes, int n_in,
                              void* d_out, int out_size, void* d_ws, size_t ws_size,
                              hipStream_t stream) {
  const float* q    = (const float*)d_in[0];
  const float* k    = (const float*)d_in[1];
  const float* v    = (const float*)d_in[2];
  const float* mask = (const float*)d_in[3];
  const float* Wq   = (const float*)d_in[4];
  const float* bq   = (const float*)d_in[5];
  const float* Wk   = (const float*)d_in[6];
  const float* bk   = (const float*)d_in[7];
  const float* Wv   = (const float*)d_in[8];
  const float* bv   = (const float*)d_in[9];
  const float* Wo   = (const float*)d_in[10];
  const float* bo   = (const float*)d_in[11];

  // ws layout (bf16/short elements): Wt[4M] | Qp[8M] | Kp[8M] | Vpt[8M] | Wbf[8M] = 72 MiB
  short* Wt  = (short*)d_ws;
  short* Qp  = Wt + (size_t)4 * 1048576;
  short* Kp  = Qp + (size_t)8388608;
  short* Vpt = Kp + (size_t)8388608;
  short* Wbf = Vpt + (size_t)8388608;

  float* out1 = (float*)d_out;            // (B,S,1024) final output
  float* out2 = out1 + (size_t)8388608;   // (B,S,H*DV) attention weights

  cvtw_k<<<dim3(4096), dim3(256), 0, stream>>>(Wq, Wk, Wv, Wo, Wt);
  gemm_k<0><<<dim3(8, 64, 3), dim3(256), 0, stream>>>(
      q, k, v, (const short*)nullptr, (const short*)Wt, bq, bk, bv, Qp, Kp, Vpt, (float*)nullptr);
  attn_k<<<dim3(32, 64), dim3(256), 0, stream>>>(Qp, Kp, Vpt, mask, out2, Wbf);
  gemm_k<1><<<dim3(8, 64, 1), dim3(256), 0, stream>>>(
      (const float*)nullptr, (const float*)nullptr, (const float*)nullptr,
      (const short*)Wbf, (const short*)(Wt + (size_t)3 * 1048576), bo,
      (const float*)nullptr, (const float*)nullptr,
      (short*)nullptr, (short*)nullptr, (short*)nullptr, out1);
}

// Round 3
// 471.193 us; speedup vs baseline: 1.4673x; 1.4673x over previous
//
#include <hip/hip_runtime.h>
#include <hip/hip_bf16.h>

// Problem constants: B=4, S=2048, D=1024, H=16, DK=DV=64
typedef __attribute__((ext_vector_type(8))) short bf16x8;  // 8 bf16 = 4 VGPR
typedef __attribute__((ext_vector_type(8))) short short8v;
typedef __attribute__((ext_vector_type(4))) float f32x4;   // MFMA acc

__device__ __forceinline__ short f2bf(float x) {
  union { __hip_bfloat16 h; short s; } u;
  u.h = __float2bfloat16(x);  // RNE; compiler packs pairs to v_cvt_pk_bf16_f32 (m240)
  return u.s;
}

__device__ __forceinline__ void async16(const void* g, void* l) {
  __builtin_amdgcn_global_load_lds(
      (const __attribute__((address_space(1))) unsigned int*)g,
      (__attribute__((address_space(3))) unsigned int*)l, 16, 0, 0);
}

// Stage a 64x64 bf16 tile (8KB) into LDS [64 rows][128B], read-swizzle
// byte ^ ((row&7)<<4), applied on the per-lane GLOBAL source (m173):
// global_load_lds writes linearly (wave-uniform base + lane*16).
__device__ __forceinline__ void stage8k(const char* gbase, int rowStride, short* lds, int tid) {
  int wave = tid >> 6, lane = tid & 63;
#pragma unroll
  for (int j = 0; j < 2; ++j) {
    int chunk = wave * 128 + j * 64 + lane;   // 0..511 (16B chunks)
    int row = chunk >> 3;
    int colb = (chunk & 7) << 4;
    const char* src = gbase + row * rowStride + (colb ^ ((row & 7) << 4));
    char* dst = (char*)lds + (wave * 128 + j * 64) * 16;  // wave-uniform base
    async16(src, dst);
  }
}

// ---------------------------------------------------------------------------
// Weight convert+transpose: W[k][n] fp32 -> Wt[n][k] bf16, 4 matrices.
__global__ __launch_bounds__(256) void cvtw_k(const float* Wq, const float* Wk,
                                              const float* Wv, const float* Wo, short* Wt) {
  int t = blockIdx.x * 256 + threadIdx.x;
  int mat = t >> 18;
  int rem = t & 262143;
  int row = rem >> 8;        // k
  int col4 = rem & 255;      // n/4
  const float* src = mat == 0 ? Wq : (mat == 1 ? Wk : (mat == 2 ? Wv : Wo));
  float4 v = *(const float4*)(src + (size_t)row * 1024 + col4 * 4);
  short* dstm = Wt + (size_t)mat * 1048576;
  int n = col4 * 4;
  dstm[(size_t)(n + 0) * 1024 + row] = f2bf(v.x);
  dstm[(size_t)(n + 1) * 1024 + row] = f2bf(v.y);
  dstm[(size_t)(n + 2) * 1024 + row] = f2bf(v.z);
  dstm[(size_t)(n + 3) * 1024 + row] = f2bf(v.w);
}

// Activation convert: fp32 (B,S,D) -> bf16 same layout, 3 tensors.
__global__ __launch_bounds__(256) void cvta_k(const float* q, const float* k,
                                              const float* v, short* out) {
  int z = blockIdx.y;
  const float* src = z == 0 ? q : (z == 1 ? k : v);
  size_t base = ((size_t)blockIdx.x * 256 + threadIdx.x) * 8;
  float4 a = *(const float4*)(src + base);
  float4 b2 = *(const float4*)(src + base + 4);
  short8v h;
  h[0] = f2bf(a.x);  h[1] = f2bf(a.y);  h[2] = f2bf(a.z);  h[3] = f2bf(a.w);
  h[4] = f2bf(b2.x); h[5] = f2bf(b2.y); h[6] = f2bf(b2.z); h[7] = f2bf(b2.w);
  *(short8v*)(out + (size_t)z * 8388608 + base) = h;
}

// ---------------------------------------------------------------------------
// GEMM: C = A(8192x1024, bf16 row-major) * W^T-stored(1024x1024 bf16) + bias.
// MODE 0: z in {0,1}: Q (scaled 1/8) / K -> bf16 (bh,s,d). SWAPPED mfma (C^T).
// MODE 1: V -> bf16 transposed (bh,d,s). Normal mfma.
// MODE 2: out-projection -> fp32 d_out. SWAPPED mfma.
// 128x128 tile, BK=32, 4 waves, global_load_lds staging with source-side
// swizzle slot^((row>>1)&3) -> 2-way (free) ds_read_b128 fragments.
template <int MODE>
__global__ __launch_bounds__(256) void gemm_k(
    const short* Ab, const short* Wt, const float* bias0, const float* bias1,
    short* Qp, short* Kp, short* Vpt, float* outF) {
  __shared__ short As[2][128 * 32];
  __shared__ short Bs[2][128 * 32];
  int tid = threadIdx.x, lane = tid & 63, wave = tid >> 6;
  int g = lane >> 4, c = lane & 15;
  int n0 = blockIdx.x * 128, m0 = blockIdx.y * 128, z = blockIdx.z;

  const short* Az = (MODE == 0) ? Ab + (size_t)z * 8388608 : Ab;
  const short* Wz = (MODE == 0) ? Wt + (size_t)z * 1048576 : Wt;
  const float* bias = (MODE == 0) ? (z == 0 ? bias0 : bias1) : bias0;

  auto stage = [&](int ks, int buf) {
    const char* ga = (const char*)Az + ((size_t)m0 * 1024 + ks * 32) * 2;
    const char* gb = (const char*)Wz + ((size_t)n0 * 1024 + ks * 32) * 2;
#pragma unroll
    for (int i = 0; i < 2; ++i) {
      int ch = i * 256 + tid;
      int row = ch >> 2, slot = ch & 3;
      int sw = ((row >> 1) & 3) << 4;
      char* dstA = (char*)&As[buf][0] + (i * 256 + wave * 64) * 16;  // wave-uniform
      char* dstB = (char*)&Bs[buf][0] + (i * 256 + wave * 64) * 16;
      async16(ga + (size_t)row * 2048 + ((slot << 4) ^ sw), dstA);
      async16(gb + (size_t)row * 2048 + ((slot << 4) ^ sw), dstB);
    }
  };

  f32x4 acc[4][4];
#pragma unroll
  for (int i = 0; i < 4; ++i)
#pragma unroll
    for (int j = 0; j < 4; ++j) acc[i][j] = (f32x4){0.f, 0.f, 0.f, 0.f};

  int wr = (wave >> 1) * 64, wc = (wave & 1) * 64;

  stage(0, 0);
  for (int ks = 0; ks < 32; ++ks) {
    __syncthreads();                       // drains vmcnt; staged buffer ready
    if (ks + 1 < 32) stage(ks + 1, (ks & 1) ^ 1);
    int cur = ks & 1;
    bf16x8 af[4], bfv[4];
#pragma unroll
    for (int mt = 0; mt < 4; ++mt) {
      int r_ = wr + mt * 16 + c;
      af[mt] = *(const bf16x8*)((const char*)&As[cur][0] + r_ * 64 +
                                ((g << 4) ^ ((((r_ >> 1) & 3)) << 4)));
    }
#pragma unroll
    for (int nt = 0; nt < 4; ++nt) {
      int r_ = wc + nt * 16 + c;
      bfv[nt] = *(const bf16x8*)((const char*)&Bs[cur][0] + r_ * 64 +
                                 ((g << 4) ^ ((((r_ >> 1) & 3)) << 4)));
    }
#pragma unroll
    for (int mt = 0; mt < 4; ++mt)
#pragma unroll
      for (int nt = 0; nt < 4; ++nt) {
        if (MODE == 1)
          acc[mt][nt] = __builtin_amdgcn_mfma_f32_16x16x32_bf16(af[mt], bfv[nt], acc[mt][nt], 0, 0, 0);
        else
          acc[mt][nt] = __builtin_amdgcn_mfma_f32_16x16x32_bf16(bfv[nt], af[mt], acc[mt][nt], 0, 0, 0);
      }
  }

  if (MODE == 0) {
    // C^T: acc[mt][nt][r] = C[m][n= nb+r]
    short* dst0 = (z == 0) ? Qp : Kp;
    float scale = (z == 0) ? 0.125f : 1.f;
#pragma unroll
    for (int nt = 0; nt < 4; ++nt) {
      int nb = n0 + wc + nt * 16 + g * 4;
      float4 b4 = *(const float4*)(bias + nb);
      int d0 = nb & 63, nh = nb >> 6;
#pragma unroll
      for (int mt = 0; mt < 4; ++mt) {
        int m = m0 + wr + mt * 16 + c;
        int bh = (m >> 11) * 16 + nh;
        short4 hv;
        hv.x = f2bf((acc[mt][nt][0] + b4.x) * scale);
        hv.y = f2bf((acc[mt][nt][1] + b4.y) * scale);
        hv.z = f2bf((acc[mt][nt][2] + b4.z) * scale);
        hv.w = f2bf((acc[mt][nt][3] + b4.w) * scale);
        *(short4*)(dst0 + ((size_t)bh * 2048 + (m & 2047)) * 64 + d0) = hv;
      }
    }
  } else if (MODE == 1) {
    // C: acc[mt][nt][r] = C[m= mb+r][n]; r runs along s -> short4 into Vpt^T
#pragma unroll
    for (int nt = 0; nt < 4; ++nt) {
      int n = n0 + wc + nt * 16 + c;
      float bb = bias[n];
      int d = n & 63, nh = n >> 6;
#pragma unroll
      for (int mt = 0; mt < 4; ++mt) {
        int mb = m0 + wr + mt * 16 + g * 4;
        int bh = (mb >> 11) * 16 + nh;
        short4 hv;
        hv.x = f2bf(acc[mt][nt][0] + bb);
        hv.y = f2bf(acc[mt][nt][1] + bb);
        hv.z = f2bf(acc[mt][nt][2] + bb);
        hv.w = f2bf(acc[mt][nt][3] + bb);
        *(short4*)(Vpt + ((size_t)bh * 64 + d) * 2048 + (mb & 2047)) = hv;
      }
    }
  } else {
    // C^T: r runs along n -> float4 rows of out
#pragma unroll
    for (int nt = 0; nt < 4; ++nt) {
      int nb = n0 + wc + nt * 16 + g * 4;
      float4 b4 = *(const float4*)(bias + nb);
#pragma unroll
      for (int mt = 0; mt < 4; ++mt) {
        int m = m0 + wr + mt * 16 + c;
        float4 o;
        o.x = acc[mt][nt][0] + b4.x;
        o.y = acc[mt][nt][1] + b4.y;
        o.z = acc[mt][nt][2] + b4.z;
        o.w = acc[mt][nt][3] + b4.w;
        *(float4*)(outF + (size_t)m * 1024 + nb) = o;
      }
    }
  }
}

// ---------------------------------------------------------------------------
// Flash attention, SWAPPED operands: S^T = mfma(K,Q) so the kv axis is
// lane-local (16 values in regs) -> softmax reduce = 15 VALU + 2 shfl.
// PV: O^T = mfma(V^T, P). Defer-max (T13, THR=8).
__global__ __launch_bounds__(256) void attn_k(const short* Qp, const short* Kp,
                                              const short* Vpt, const float* mask,
                                              float* outW, short* wbf) {
  __shared__ short Qs[64 * 64];
  __shared__ short Ks[2][64 * 64];
  __shared__ short Vs[2][64 * 64];
  __shared__ short Ps[64 * 64];
  int tid = threadIdx.x, lane = tid & 63, wave = tid >> 6;
  int g = lane >> 4, c = lane & 15;
  int qt = blockIdx.x, bh = blockIdx.y;
  int b = bh >> 4, h = bh & 15;

  const char* Qg = (const char*)Qp + ((size_t)bh * 2048 + qt * 64) * 128;
  const char* Kg = (const char*)Kp + (size_t)bh * 2048 * 128;
  const char* Vg = (const char*)Vpt + (size_t)bh * 64 * 4096;

  stage8k(Qg, 128, Qs, tid);
  stage8k(Kg, 128, Ks[0], tid);
  stage8k(Vg, 4096, Vs[0], tid);

  f32x4 acco[4];
#pragma unroll
  for (int i = 0; i < 4; ++i) acco[i] = (f32x4){0.f, 0.f, 0.f, 0.f};
  float mrun = -1e30f, lrun = 0.f;

  __syncthreads();  // Q + tile0 staged (vmcnt drained)

  int qrow = wave * 16 + c;  // this lane's q row (col index in S^T)
  bf16x8 aq[2];
#pragma unroll
  for (int k2 = 0; k2 < 2; ++k2)
    aq[k2] = *(const bf16x8*)((const char*)Qs + qrow * 128 +
                              ((k2 * 64 + g * 16) ^ ((qrow & 7) << 4)));

  int cur = 0;
  for (int t = 0; t < 32; ++t) {
    if (t + 1 < 32) {
      stage8k(Kg + (size_t)(t + 1) * 8192, 128, Ks[cur ^ 1], tid);
      stage8k(Vg + (size_t)(t + 1) * 128, 4096, Vs[cur ^ 1], tid);
    }
    // ---- S^T[kv][q]: A=K rows(kv), B=Q cols(q) ----
    f32x4 sc[4];
#pragma unroll
    for (int n = 0; n < 4; ++n) {
      sc[n] = (f32x4){0.f, 0.f, 0.f, 0.f};
#pragma unroll
      for (int k2 = 0; k2 < 2; ++k2) {
        int row = n * 16 + c;
        bf16x8 bk = *(const bf16x8*)((const char*)&Ks[cur][0] + row * 128 +
                                     ((k2 * 64 + g * 16) ^ ((row & 7) << 4)));
        sc[n] = __builtin_amdgcn_mfma_f32_16x16x32_bf16(bk, aq[k2], sc[n], 0, 0, 0);
      }
    }
    // ---- mask (varies along kv = n*16+g*4+r) ----
#pragma unroll
    for (int n = 0; n < 4; ++n) {
      float4 mk = *(const float4*)(mask + (size_t)b * 2048 + t * 64 + n * 16 + g * 4);
      sc[n][0] += mk.x; sc[n][1] += mk.y; sc[n][2] += mk.z; sc[n][3] += mk.w;
    }
    // ---- online softmax along kv: in-lane + 2 shfl ----
    float tmax = sc[0][0];
#pragma unroll
    for (int n = 0; n < 4; ++n)
#pragma unroll
      for (int r = 0; r < 4; ++r) tmax = fmaxf(tmax, sc[n][r]);
    tmax = fmaxf(tmax, __shfl_xor(tmax, 16));
    tmax = fmaxf(tmax, __shfl_xor(tmax, 32));
    if (!__all(tmax <= mrun + 8.0f)) {   // defer-max (T13)
      float mnew = fmaxf(mrun, tmax);
      float fsc = __expf(mrun - mnew);
      mrun = mnew;
      lrun *= fsc;
#pragma unroll
      for (int n = 0; n < 4; ++n)
#pragma unroll
        for (int r = 0; r < 4; ++r) acco[n][r] *= fsc;
    }
    float p[4][4], rs = 0.f;
#pragma unroll
    for (int n = 0; n < 4; ++n)
#pragma unroll
      for (int r = 0; r < 4; ++r) {
        p[n][r] = __expf(sc[n][r] - mrun);
        rs += p[n][r];
      }
    rs += __shfl_xor(rs, 16);
    rs += __shfl_xor(rs, 32);
    lrun += rs;
    // ---- P -> LDS as [q][kv] (bf16, swizzled, short4 = 4 consecutive kv) ----
#pragma unroll
    for (int n = 0; n < 4; ++n) {
      short4 hv;
      hv.x = f2bf(p[n][0]); hv.y = f2bf(p[n][1]);
      hv.z = f2bf(p[n][2]); hv.w = f2bf(p[n][3]);
      int colb = (n * 32 + g * 8) ^ ((qrow & 7) << 4);
      *(short4*)((char*)Ps + qrow * 128 + colb) = hv;
    }
    // ---- O^T += V^T P : A=V^T rows(d), B=P cols(q); wave reads only its own
    //      16 P rows (which it wrote itself -> wave-local DS ordering) ----
#pragma unroll
    for (int k2 = 0; k2 < 2; ++k2) {
      bf16x8 ap = *(const bf16x8*)((const char*)Ps + qrow * 128 +
                                   ((k2 * 64 + g * 16) ^ ((qrow & 7) << 4)));
#pragma unroll
      for (int n2 = 0; n2 < 4; ++n2) {
        int rv = n2 * 16 + c;
        bf16x8 bv = *(const bf16x8*)((const char*)&Vs[cur][0] + rv * 128 +
                                     ((k2 * 64 + g * 16) ^ ((rv & 7) << 4)));
        acco[n2] = __builtin_amdgcn_mfma_f32_16x16x32_bf16(bv, ap, acco[n2], 0, 0, 0);
      }
    }
    __syncthreads();
    cur ^= 1;
  }
  // ---- epilogue: O^T[d][q] / l -> float4 along d ----
  float inv = 1.0f / lrun;
  int srow = qt * 64 + qrow;
#pragma unroll
  for (int n = 0; n < 4; ++n) {
    int col0 = h * 64 + n * 16 + g * 4;
    size_t idx = ((size_t)b * 2048 + srow) * 1024 + col0;
    float4 o;
    o.x = acco[n][0] * inv; o.y = acco[n][1] * inv;
    o.z = acco[n][2] * inv; o.w = acco[n][3] * inv;
    *(float4*)(outW + idx) = o;
    short4 hv;
    hv.x = f2bf(o.x); hv.y = f2bf(o.y); hv.z = f2bf(o.z); hv.w = f2bf(o.w);
    *(short4*)(wbf + idx) = hv;
  }
}

// ---------------------------------------------------------------------------
extern "C" void kernel_launch(void* const* d_in, const int* in_sizes, int n_in,
                              void* d_out, int out_size, void* d_ws, size_t ws_size,
                              hipStream_t stream) {
  const float* q    = (const float*)d_in[0];
  const float* k    = (const float*)d_in[1];
  const float* v    = (const float*)d_in[2];
  const float* mask = (const float*)d_in[3];
  const float* Wq   = (const float*)d_in[4];
  const float* bq   = (const float*)d_in[5];
  const float* Wk   = (const float*)d_in[6];
  const float* bk   = (const float*)d_in[7];
  const float* Wv   = (const float*)d_in[8];
  const float* bv   = (const float*)d_in[9];
  const float* Wo   = (const float*)d_in[10];
  const float* bo   = (const float*)d_in[11];

  // ws (shorts, 72 MiB total — round-1-proven size):
  //   Wt[4M] | Qp[8M] | Kp[8M] | Vpt[8M] | Wbf[8M]
  short* Wt  = (short*)d_ws;
  short* Qp  = Wt + (size_t)4 * 1048576;
  short* Kp  = Qp + (size_t)8388608;
  short* Vpt = Kp + (size_t)8388608;
  short* Wbf = Vpt + (size_t)8388608;

  float* out1 = (float*)d_out;            // (B,S,1024) final output
  float* out2 = out1 + (size_t)8388608;   // (B,S,H*DV) attention weights

  // Abf (bf16 activations, 48 MB) lives in d_out — dead before out1/out2 are
  // written: cvta fills d_out[0,48MB); QKV GEMMs consume it; attn then writes
  // out2 [32,64MB); gemm<2> finally writes out1 [0,32MB).
  short* Abf = (short*)d_out;

  cvtw_k<<<dim3(4096), dim3(256), 0, stream>>>(Wq, Wk, Wv, Wo, Wt);
  cvta_k<<<dim3(4096, 3), dim3(256), 0, stream>>>(q, k, v, Abf);
  gemm_k<0><<<dim3(8, 64, 2), dim3(256), 0, stream>>>(
      Abf, Wt, bq, bk, Qp, Kp, (short*)nullptr, (float*)nullptr);
  gemm_k<1><<<dim3(8, 64, 1), dim3(256), 0, stream>>>(
      Abf + (size_t)2 * 8388608, Wt + (size_t)2 * 1048576, bv, (const float*)nullptr,
      (short*)nullptr, (short*)nullptr, Vpt, (float*)nullptr);
  attn_k<<<dim3(32, 64), dim3(256), 0, stream>>>(Qp, Kp, Vpt, mask, out2, Wbf);
  gemm_k<2><<<dim3(8, 64, 1), dim3(256), 0, stream>>>(
      Wbf, Wt + (size_t)3 * 1048576, bo, (const float*)nullptr,
      (short*)nullptr, (short*)nullptr, (short*)nullptr, out1);
}

// Round 4
// 426.104 us; speedup vs baseline: 1.6226x; 1.1058x over previous
//
#include <hip/hip_runtime.h>
#include <hip/hip_bf16.h>

// Problem constants: B=4, S=2048, D=1024, H=16, DK=DV=64
typedef __attribute__((ext_vector_type(8))) short bf16x8;  // 8 bf16 = 4 VGPR
typedef __attribute__((ext_vector_type(8))) short short8v;
typedef __attribute__((ext_vector_type(4))) float f32x4;   // MFMA acc

__device__ __forceinline__ short f2bf(float x) {
  union { __hip_bfloat16 h; short s; } u;
  u.h = __float2bfloat16(x);  // RNE; pairs pack to v_cvt_pk_bf16_f32
  return u.s;
}

__device__ __forceinline__ void async16(const void* g, void* l) {
  __builtin_amdgcn_global_load_lds(
      (const __attribute__((address_space(1))) unsigned int*)g,
      (__attribute__((address_space(3))) unsigned int*)l, 16, 0, 0);
}

// Counted vmcnt waits (T4): keep prefetch in flight across barriers.
#define VM_WAIT4 do { asm volatile("s_waitcnt vmcnt(4)" ::: "memory"); \
                      __builtin_amdgcn_sched_barrier(0); } while (0)
#define VM_WAIT0 do { asm volatile("s_waitcnt vmcnt(0)" ::: "memory"); \
                      __builtin_amdgcn_sched_barrier(0); } while (0)

// Stage a 64x64 bf16 tile (8KB) into LDS [64 rows][128B], read-swizzle
// byte ^ ((row&7)<<4), applied on the per-lane GLOBAL source (m173):
// global_load_lds writes linearly (wave-uniform base + lane*16).
// Each wave stages its own 16 rows (wave-local).
__device__ __forceinline__ void stage8k(const char* gbase, int rowStride, short* lds, int tid) {
  int wave = tid >> 6, lane = tid & 63;
#pragma unroll
  for (int j = 0; j < 2; ++j) {
    int chunk = wave * 128 + j * 64 + lane;   // 0..511 (16B chunks)
    int row = chunk >> 3;
    int colb = (chunk & 7) << 4;
    const char* src = gbase + row * rowStride + (colb ^ ((row & 7) << 4));
    char* dst = (char*)lds + (wave * 128 + j * 64) * 16;  // wave-uniform base
    async16(src, dst);
  }
}

// ---------------------------------------------------------------------------
// Weight convert+transpose via LDS tile: W[k][n] fp32 -> Wt[n][k] bf16.
// Coalesced float4 reads, coalesced 16B writes (old version scattered 2B
// writes at 2KB stride -> ~32x write amplification).
__global__ __launch_bounds__(256) void cvtw_k(const float* Wq, const float* Wk,
                                              const float* Wv, const float* Wo, short* Wt) {
  __shared__ short T[64 * 72];  // [kk][nn], pitch 72 shorts
  int mat = blockIdx.z;
  const float* src = mat == 0 ? Wq : (mat == 1 ? Wk : (mat == 2 ? Wv : Wo));
  int n0 = blockIdx.x * 64, k0 = blockIdx.y * 64;
  int tid = threadIdx.x;
#pragma unroll
  for (int i = 0; i < 4; ++i) {
    int f = i * 256 + tid;            // float4 index 0..1023
    int kk = f >> 4, nn4 = (f & 15) * 4;
    float4 v = *(const float4*)(src + (size_t)(k0 + kk) * 1024 + n0 + nn4);
    short* d = &T[kk * 72 + nn4];
    d[0] = f2bf(v.x); d[1] = f2bf(v.y); d[2] = f2bf(v.z); d[3] = f2bf(v.w);
  }
  __syncthreads();
  short* dstm = Wt + (size_t)mat * 1048576;
#pragma unroll
  for (int i = 0; i < 2; ++i) {
    int cidx = i * 256 + tid;         // 0..511: nn(64) x kc(8)
    int nn = cidx >> 3, kc = (cidx & 7) * 8;
    short8v o;
#pragma unroll
    for (int j = 0; j < 8; ++j) o[j] = T[(kc + j) * 72 + nn];
    *(short8v*)(dstm + (size_t)(n0 + nn) * 1024 + k0 + kc) = o;
  }
}

// Activation convert: fp32 (B,S,D) -> bf16 same layout, 3 tensors.
__global__ __launch_bounds__(256) void cvta_k(const float* q, const float* k,
                                              const float* v, short* out) {
  int z = blockIdx.y;
  const float* src = z == 0 ? q : (z == 1 ? k : v);
  size_t base = ((size_t)blockIdx.x * 256 + threadIdx.x) * 8;
  float4 a = *(const float4*)(src + base);
  float4 b2 = *(const float4*)(src + base + 4);
  short8v h;
  h[0] = f2bf(a.x);  h[1] = f2bf(a.y);  h[2] = f2bf(a.z);  h[3] = f2bf(a.w);
  h[4] = f2bf(b2.x); h[5] = f2bf(b2.y); h[6] = f2bf(b2.z); h[7] = f2bf(b2.w);
  *(short8v*)(out + (size_t)z * 8388608 + base) = h;
}

// ---------------------------------------------------------------------------
// GEMM: C = A(8192x1024, bf16 row-major) * W^T-stored(1024x1024 bf16) + bias.
// MODE 0: z in {0,1}: Q (scaled 1/8) / K -> bf16 (bh,s,d). SWAPPED mfma (C^T).
// MODE 1: V -> bf16 transposed (bh,d,s). Normal mfma.
// MODE 2: out-projection -> fp32 d_out. SWAPPED mfma.
// 128x128 tile, BK=32, 4 waves; counted-vmcnt 2-barrier pipeline (T4) +
// setprio (T5) + bijective XCD swizzle (T1, nwg=512 per z-slice).
template <int MODE>
__global__ __launch_bounds__(256) void gemm_k(
    const short* Ab, const short* Wt, const float* bias0, const float* bias1,
    short* Qp, short* Kp, short* Vpt, float* outF) {
  __shared__ short As[2][128 * 32];
  __shared__ short Bs[2][128 * 32];
  int tid = threadIdx.x, lane = tid & 63, wave = tid >> 6;
  int g = lane >> 4, c = lane & 15;
  // XCD swizzle: nwg = 512 (%8==0) -> logical = (orig%8)*64 + orig/8
  int orig = blockIdx.x + blockIdx.y * 8;
  int wg = (orig & 7) * 64 + (orig >> 3);
  int n0 = (wg & 7) * 128, m0 = (wg >> 3) * 128, z = blockIdx.z;

  const short* Az = (MODE == 0) ? Ab + (size_t)z * 8388608 : Ab;
  const short* Wz = (MODE == 0) ? Wt + (size_t)z * 1048576 : Wt;
  const float* bias = (MODE == 0) ? (z == 0 ? bias0 : bias1) : bias0;

  auto stage = [&](int ks, int buf) {
    const char* ga = (const char*)Az + ((size_t)m0 * 1024 + ks * 32) * 2;
    const char* gb = (const char*)Wz + ((size_t)n0 * 1024 + ks * 32) * 2;
#pragma unroll
    for (int i = 0; i < 2; ++i) {
      int ch = i * 256 + tid;
      int row = ch >> 2, slot = ch & 3;
      int sw = ((row >> 1) & 3) << 4;
      char* dstA = (char*)&As[buf][0] + (i * 256 + wave * 64) * 16;  // wave-uniform
      char* dstB = (char*)&Bs[buf][0] + (i * 256 + wave * 64) * 16;
      async16(ga + (size_t)row * 2048 + ((slot << 4) ^ sw), dstA);
      async16(gb + (size_t)row * 2048 + ((slot << 4) ^ sw), dstB);
    }
  };

  f32x4 acc[4][4];
#pragma unroll
  for (int i = 0; i < 4; ++i)
#pragma unroll
    for (int j = 0; j < 4; ++j) acc[i][j] = (f32x4){0.f, 0.f, 0.f, 0.f};

  int wr = (wave >> 1) * 64, wc = (wave & 1) * 64;

  stage(0, 0);
  for (int ks = 0; ks < 32; ++ks) {
    if (ks + 1 < 32) { stage(ks + 1, (ks & 1) ^ 1); VM_WAIT4; }
    else             { VM_WAIT0; }
    __builtin_amdgcn_s_barrier();      // all waves' stage(ks) landed
    int cur = ks & 1;
    bf16x8 af[4], bfv[4];
#pragma unroll
    for (int mt = 0; mt < 4; ++mt) {
      int r_ = wr + mt * 16 + c;
      af[mt] = *(const bf16x8*)((const char*)&As[cur][0] + r_ * 64 +
                                ((g << 4) ^ ((((r_ >> 1) & 3)) << 4)));
    }
#pragma unroll
    for (int nt = 0; nt < 4; ++nt) {
      int r_ = wc + nt * 16 + c;
      bfv[nt] = *(const bf16x8*)((const char*)&Bs[cur][0] + r_ * 64 +
                                 ((g << 4) ^ ((((r_ >> 1) & 3)) << 4)));
    }
    __builtin_amdgcn_s_setprio(1);
#pragma unroll
    for (int mt = 0; mt < 4; ++mt)
#pragma unroll
      for (int nt = 0; nt < 4; ++nt) {
        if (MODE == 1)
          acc[mt][nt] = __builtin_amdgcn_mfma_f32_16x16x32_bf16(af[mt], bfv[nt], acc[mt][nt], 0, 0, 0);
        else
          acc[mt][nt] = __builtin_amdgcn_mfma_f32_16x16x32_bf16(bfv[nt], af[mt], acc[mt][nt], 0, 0, 0);
      }
    __builtin_amdgcn_s_setprio(0);
    __builtin_amdgcn_s_barrier();      // reads of buf[cur] done -> next stage may overwrite
  }

  if (MODE == 0) {
    // C^T: acc[mt][nt][r] = C[m][n = nb+r]
    short* dst0 = (z == 0) ? Qp : Kp;
    float scale = (z == 0) ? 0.125f : 1.f;
#pragma unroll
    for (int nt = 0; nt < 4; ++nt) {
      int nb = n0 + wc + nt * 16 + g * 4;
      float4 b4 = *(const float4*)(bias + nb);
      int d0 = nb & 63, nh = nb >> 6;
#pragma unroll
      for (int mt = 0; mt < 4; ++mt) {
        int m = m0 + wr + mt * 16 + c;
        int bh = (m >> 11) * 16 + nh;
        short4 hv;
        hv.x = f2bf((acc[mt][nt][0] + b4.x) * scale);
        hv.y = f2bf((acc[mt][nt][1] + b4.y) * scale);
        hv.z = f2bf((acc[mt][nt][2] + b4.z) * scale);
        hv.w = f2bf((acc[mt][nt][3] + b4.w) * scale);
        *(short4*)(dst0 + ((size_t)bh * 2048 + (m & 2047)) * 64 + d0) = hv;
      }
    }
  } else if (MODE == 1) {
    // C: acc[mt][nt][r] = C[m = mb+r][n]; r runs along s -> short4 into Vpt^T
#pragma unroll
    for (int nt = 0; nt < 4; ++nt) {
      int n = n0 + wc + nt * 16 + c;
      float bb = bias[n];
      int d = n & 63, nh = n >> 6;
#pragma unroll
      for (int mt = 0; mt < 4; ++mt) {
        int mb = m0 + wr + mt * 16 + g * 4;
        int bh = (mb >> 11) * 16 + nh;
        short4 hv;
        hv.x = f2bf(acc[mt][nt][0] + bb);
        hv.y = f2bf(acc[mt][nt][1] + bb);
        hv.z = f2bf(acc[mt][nt][2] + bb);
        hv.w = f2bf(acc[mt][nt][3] + bb);
        *(short4*)(Vpt + ((size_t)bh * 64 + d) * 2048 + (mb & 2047)) = hv;
      }
    }
  } else {
    // C^T: r runs along n -> float4 rows of out
#pragma unroll
    for (int nt = 0; nt < 4; ++nt) {
      int nb = n0 + wc + nt * 16 + g * 4;
      float4 b4 = *(const float4*)(bias + nb);
#pragma unroll
      for (int mt = 0; mt < 4; ++mt) {
        int m = m0 + wr + mt * 16 + c;
        float4 o;
        o.x = acc[mt][nt][0] + b4.x;
        o.y = acc[mt][nt][1] + b4.y;
        o.z = acc[mt][nt][2] + b4.z;
        o.w = acc[mt][nt][3] + b4.w;
        *(float4*)(outF + (size_t)m * 1024 + nb) = o;
      }
    }
  }
}

// ---------------------------------------------------------------------------
// Flash attention, SWAPPED operands: S^T = mfma(K,Q), kv axis lane-local.
// Counted-vmcnt 2-barrier pipeline; Ps aliases Qs (LDS 40KB -> 4 blocks/CU);
// XCD swizzle groups 8 bh (4MB K/V = one L2) per XCD.
__global__ __launch_bounds__(256) void attn_k(const short* Qp, const short* Kp,
                                              const short* Vpt, const float* mask,
                                              float* outW, short* wbf) {
  __shared__ short Qs[64 * 64];        // prologue: Q tile; loop: P tile (alias)
  __shared__ short Ks[2][64 * 64];
  __shared__ short Vs[2][64 * 64];
  short* Ps = Qs;
  int tid = threadIdx.x, lane = tid & 63, wave = tid >> 6;
  int g = lane >> 4, c = lane & 15;
  // XCD swizzle: nwg = 2048 -> logical = (orig%8)*256 + orig/8
  int orig = blockIdx.x + blockIdx.y * 32;
  int wg = (orig & 7) * 256 + (orig >> 3);
  int qt = wg & 31, bh = wg >> 5;
  int b = bh >> 4, h = bh & 15;

  const char* Qg = (const char*)Qp + ((size_t)bh * 2048 + qt * 64) * 128;
  const char* Kg = (const char*)Kp + (size_t)bh * 2048 * 128;
  const char* Vg = (const char*)Vpt + (size_t)bh * 64 * 4096;

  stage8k(Qg, 128, Qs, tid);           // issued FIRST (oldest in vmcnt order)
  stage8k(Kg, 128, Ks[0], tid);
  stage8k(Vg, 4096, Vs[0], tid);

  f32x4 acco[4];
#pragma unroll
  for (int i = 0; i < 4; ++i) acco[i] = (f32x4){0.f, 0.f, 0.f, 0.f};
  float mrun = -1e30f, lrun = 0.f;

  VM_WAIT4;  // waits the 2 oldest (= own Q rows; aq rows are wave-local)
  int qrow = wave * 16 + c;            // this lane's q row (col index in S^T)
  bf16x8 aq[2];
#pragma unroll
  for (int k2 = 0; k2 < 2; ++k2)
    aq[k2] = *(const bf16x8*)((const char*)Qs + qrow * 128 +
                              ((k2 * 64 + g * 16) ^ ((qrow & 7) << 4)));

  int cur = 0;
  for (int t = 0; t < 32; ++t) {
    // mask loads FIRST (so vmcnt(4) below never drains the new stage)
    float4 mk[4];
#pragma unroll
    for (int n = 0; n < 4; ++n)
      mk[n] = *(const float4*)(mask + (size_t)b * 2048 + t * 64 + n * 16 + g * 4);
    __builtin_amdgcn_sched_barrier(0);
    if (t + 1 < 32) {
      stage8k(Kg + (size_t)(t + 1) * 8192, 128, Ks[cur ^ 1], tid);
      stage8k(Vg + (size_t)(t + 1) * 128, 4096, Vs[cur ^ 1], tid);
    }
    VM_WAIT4;                          // own stage(t) + mask landed; stage(t+1) in flight
    __builtin_amdgcn_s_barrier();      // all waves' stage(t) landed
    // ---- S^T[kv][q]: A=K rows(kv), B=Q cols(q) ----
    f32x4 sc[4];
    __builtin_amdgcn_s_setprio(1);
#pragma unroll
    for (int n = 0; n < 4; ++n) {
      sc[n] = (f32x4){0.f, 0.f, 0.f, 0.f};
#pragma unroll
      for (int k2 = 0; k2 < 2; ++k2) {
        int row = n * 16 + c;
        bf16x8 bk = *(const bf16x8*)((const char*)&Ks[cur][0] + row * 128 +
                                     ((k2 * 64 + g * 16) ^ ((row & 7) << 4)));
        sc[n] = __builtin_amdgcn_mfma_f32_16x16x32_bf16(bk, aq[k2], sc[n], 0, 0, 0);
      }
    }
    __builtin_amdgcn_s_setprio(0);
    // ---- mask (varies along kv = n*16 + g*4 + r) ----
#pragma unroll
    for (int n = 0; n < 4; ++n) {
      sc[n][0] += mk[n].x; sc[n][1] += mk[n].y;
      sc[n][2] += mk[n].z; sc[n][3] += mk[n].w;
    }
    // ---- online softmax along kv: in-lane + 2 shfl ----
    float tmax = sc[0][0];
#pragma unroll
    for (int n = 0; n < 4; ++n)
#pragma unroll
      for (int r = 0; r < 4; ++r) tmax = fmaxf(tmax, sc[n][r]);
    tmax = fmaxf(tmax, __shfl_xor(tmax, 16));
    tmax = fmaxf(tmax, __shfl_xor(tmax, 32));
    if (!__all(tmax <= mrun + 8.0f)) {   // defer-max (T13)
      float mnew = fmaxf(mrun, tmax);
      float fsc = __expf(mrun - mnew);
      mrun = mnew;
      lrun *= fsc;
#pragma unroll
      for (int n = 0; n < 4; ++n)
#pragma unroll
        for (int r = 0; r < 4; ++r) acco[n][r] *= fsc;
    }
    float p[4][4], rs = 0.f;
#pragma unroll
    for (int n = 0; n < 4; ++n)
#pragma unroll
      for (int r = 0; r < 4; ++r) {
        p[n][r] = __expf(sc[n][r] - mrun);
        rs += p[n][r];
      }
    rs += __shfl_xor(rs, 16);
    rs += __shfl_xor(rs, 32);
    lrun += rs;
    // ---- P -> LDS [q][kv] (wave-local rows; Ps aliases Qs) ----
#pragma unroll
    for (int n = 0; n < 4; ++n) {
      short4 hv;
      hv.x = f2bf(p[n][0]); hv.y = f2bf(p[n][1]);
      hv.z = f2bf(p[n][2]); hv.w = f2bf(p[n][3]);
      int colb = (n * 32 + g * 8) ^ ((qrow & 7) << 4);
      *(short4*)((char*)Ps + qrow * 128 + colb) = hv;
    }
    // ---- O^T += V^T P : A=V^T rows(d), B=P cols(q) ----
    __builtin_amdgcn_s_setprio(1);
#pragma unroll
    for (int k2 = 0; k2 < 2; ++k2) {
      bf16x8 ap = *(const bf16x8*)((const char*)Ps + qrow * 128 +
                                   ((k2 * 64 + g * 16) ^ ((qrow & 7) << 4)));
#pragma unroll
      for (int n2 = 0; n2 < 4; ++n2) {
        int rv = n2 * 16 + c;
        bf16x8 bv = *(const bf16x8*)((const char*)&Vs[cur][0] + rv * 128 +
                                     ((k2 * 64 + g * 16) ^ ((rv & 7) << 4)));
        acco[n2] = __builtin_amdgcn_mfma_f32_16x16x32_bf16(bv, ap, acco[n2], 0, 0, 0);
      }
    }
    __builtin_amdgcn_s_setprio(0);
    __builtin_amdgcn_s_barrier();      // reads of buf[cur] done -> next stage safe
    cur ^= 1;
  }
  // ---- epilogue: O^T[d][q] / l -> float4 along d ----
  float inv = 1.0f / lrun;
  int srow = qt * 64 + qrow;
#pragma unroll
  for (int n = 0; n < 4; ++n) {
    int col0 = h * 64 + n * 16 + g * 4;
    size_t idx = ((size_t)b * 2048 + srow) * 1024 + col0;
    float4 o;
    o.x = acco[n][0] * inv; o.y = acco[n][1] * inv;
    o.z = acco[n][2] * inv; o.w = acco[n][3] * inv;
    *(float4*)(outW + idx) = o;
    short4 hv;
    hv.x = f2bf(o.x); hv.y = f2bf(o.y); hv.z = f2bf(o.z); hv.w = f2bf(o.w);
    *(short4*)(wbf + idx) = hv;
  }
}

// ---------------------------------------------------------------------------
extern "C" void kernel_launch(void* const* d_in, const int* in_sizes, int n_in,
                              void* d_out, int out_size, void* d_ws, size_t ws_size,
                              hipStream_t stream) {
  const float* q    = (const float*)d_in[0];
  const float* k    = (const float*)d_in[1];
  const float* v    = (const float*)d_in[2];
  const float* mask = (const float*)d_in[3];
  const float* Wq   = (const float*)d_in[4];
  const float* bq   = (const float*)d_in[5];
  const float* Wk   = (const float*)d_in[6];
  const float* bk   = (const float*)d_in[7];
  const float* Wv   = (const float*)d_in[8];
  const float* bv   = (const float*)d_in[9];
  const float* Wo   = (const float*)d_in[10];
  const float* bo   = (const float*)d_in[11];

  // ws (shorts, 72 MiB): Wt[4M] | Qp[8M] | Kp[8M] | Vpt[8M] | Wbf[8M]
  short* Wt  = (short*)d_ws;
  short* Qp  = Wt + (size_t)4 * 1048576;
  short* Kp  = Qp + (size_t)8388608;
  short* Vpt = Kp + (size_t)8388608;
  short* Wbf = Vpt + (size_t)8388608;

  float* out1 = (float*)d_out;            // (B,S,1024) final output
  float* out2 = out1 + (size_t)8388608;   // (B,S,H*DV) attention weights

  // Abf (bf16 activations, 48 MB) lives in d_out — dead before out1/out2 are
  // written: cvta fills d_out[0,48MB); QKV GEMMs consume it; attn then writes
  // out2 [32,64MB); gemm<2> finally writes out1 [0,32MB).
  short* Abf = (short*)d_out;

  cvtw_k<<<dim3(16, 16, 4), dim3(256), 0, stream>>>(Wq, Wk, Wv, Wo, Wt);
  cvta_k<<<dim3(4096, 3), dim3(256), 0, stream>>>(q, k, v, Abf);
  gemm_k<0><<<dim3(8, 64, 2), dim3(256), 0, stream>>>(
      Abf, Wt, bq, bk, Qp, Kp, (short*)nullptr, (float*)nullptr);
  gemm_k<1><<<dim3(8, 64, 1), dim3(256), 0, stream>>>(
      Abf + (size_t)2 * 8388608, Wt + (size_t)2 * 1048576, bv, (const float*)nullptr,
      (short*)nullptr, (short*)nullptr, Vpt, (float*)nullptr);
  attn_k<<<dim3(32, 64), dim3(256), 0, stream>>>(Qp, Kp, Vpt, mask, out2, Wbf);
  gemm_k<2><<<dim3(8, 64, 1), dim3(256), 0, stream>>>(
      Wbf, Wt + (size_t)3 * 1048576, bo, (const float*)nullptr,
      (short*)nullptr, (short*)nullptr, (short*)nullptr, out1);
}

// Round 5
// 396.550 us; speedup vs baseline: 1.7435x; 1.0745x over previous
//
#include <hip/hip_runtime.h>
#include <hip/hip_bf16.h>

// Problem constants: B=4, S=2048, D=1024, H=16, DK=DV=64
typedef __attribute__((ext_vector_type(8))) short bf16x8;  // 8 bf16 = 4 VGPR
typedef __attribute__((ext_vector_type(8))) short short8v;
typedef __attribute__((ext_vector_type(4))) float f32x4;   // MFMA acc
typedef __attribute__((ext_vector_type(2))) float f32x2;   // packed fp32 (v_pk_*)

__device__ __forceinline__ short f2bf(float x) {
  union { __hip_bfloat16 h; short s; } u;
  u.h = __float2bfloat16(x);  // RNE; pairs pack to v_cvt_pk_bf16_f32
  return u.s;
}

__device__ __forceinline__ void async16(const void* g, void* l) {
  __builtin_amdgcn_global_load_lds(
      (const __attribute__((address_space(1))) unsigned int*)g,
      (__attribute__((address_space(3))) unsigned int*)l, 16, 0, 0);
}

// Counted vmcnt waits (T4): keep prefetch in flight across barriers.
#define VM_WAIT4 do { asm volatile("s_waitcnt vmcnt(4)" ::: "memory"); \
                      __builtin_amdgcn_sched_barrier(0); } while (0)
#define VM_WAIT3 do { asm volatile("s_waitcnt vmcnt(3)" ::: "memory"); \
                      __builtin_amdgcn_sched_barrier(0); } while (0)
#define VM_WAIT0 do { asm volatile("s_waitcnt vmcnt(0)" ::: "memory"); \
                      __builtin_amdgcn_sched_barrier(0); } while (0)

// Stage a 64x64 bf16 tile (8KB) into LDS [64 rows][128B], read-swizzle
// byte ^ ((row&7)<<4), applied on the per-lane GLOBAL source (m173):
// global_load_lds writes linearly (wave-uniform base + lane*16).
__device__ __forceinline__ void stage8k(const char* gbase, int rowStride, short* lds, int tid) {
  int wave = tid >> 6, lane = tid & 63;
#pragma unroll
  for (int j = 0; j < 2; ++j) {
    int chunk = wave * 128 + j * 64 + lane;   // 0..511 (16B chunks)
    int row = chunk >> 3;
    int colb = (chunk & 7) << 4;
    const char* src = gbase + row * rowStride + (colb ^ ((row & 7) << 4));
    char* dst = (char*)lds + (wave * 128 + j * 64) * 16;  // wave-uniform base
    async16(src, dst);
  }
}

// ---------------------------------------------------------------------------
// Weight convert+transpose via LDS tile: W[k][n] fp32 -> Wt[n][k] bf16.
__global__ __launch_bounds__(256) void cvtw_k(const float* Wq, const float* Wk,
                                              const float* Wv, const float* Wo, short* Wt) {
  __shared__ short T[64 * 72];  // [kk][nn], pitch 72 shorts
  int mat = blockIdx.z;
  const float* src = mat == 0 ? Wq : (mat == 1 ? Wk : (mat == 2 ? Wv : Wo));
  int n0 = blockIdx.x * 64, k0 = blockIdx.y * 64;
  int tid = threadIdx.x;
#pragma unroll
  for (int i = 0; i < 4; ++i) {
    int f = i * 256 + tid;            // float4 index 0..1023
    int kk = f >> 4, nn4 = (f & 15) * 4;
    float4 v = *(const float4*)(src + (size_t)(k0 + kk) * 1024 + n0 + nn4);
    short* d = &T[kk * 72 + nn4];
    d[0] = f2bf(v.x); d[1] = f2bf(v.y); d[2] = f2bf(v.z); d[3] = f2bf(v.w);
  }
  __syncthreads();
  short* dstm = Wt + (size_t)mat * 1048576;
#pragma unroll
  for (int i = 0; i < 2; ++i) {
    int cidx = i * 256 + tid;         // 0..511: nn(64) x kc(8)
    int nn = cidx >> 3, kc = (cidx & 7) * 8;
    short8v o;
#pragma unroll
    for (int j = 0; j < 8; ++j) o[j] = T[(kc + j) * 72 + nn];
    *(short8v*)(dstm + (size_t)(n0 + nn) * 1024 + k0 + kc) = o;
  }
}

// Activation convert: fp32 (B,S,D) -> bf16 same layout, 3 tensors.
__global__ __launch_bounds__(256) void cvta_k(const float* q, const float* k,
                                              const float* v, short* out) {
  int z = blockIdx.y;
  const float* src = z == 0 ? q : (z == 1 ? k : v);
  size_t base = ((size_t)blockIdx.x * 256 + threadIdx.x) * 8;
  float4 a = *(const float4*)(src + base);
  float4 b2 = *(const float4*)(src + base + 4);
  short8v h;
  h[0] = f2bf(a.x);  h[1] = f2bf(a.y);  h[2] = f2bf(a.z);  h[3] = f2bf(a.w);
  h[4] = f2bf(b2.x); h[5] = f2bf(b2.y); h[6] = f2bf(b2.z); h[7] = f2bf(b2.w);
  *(short8v*)(out + (size_t)z * 8388608 + base) = h;
}

// ---------------------------------------------------------------------------
// GEMM, all-SWAPPED mfma (C^T fragments).
// MODE 0: fused QKV projection. N = 3072 (seg = n/1024 selects activation +
//         weight + bias + output tensor). 128x128 tiles, grid (24,64).
// MODE 2: out-projection -> fp32 d_out. 128x64 tiles, grid (16,64).
// Counted-vmcnt 2-barrier pipeline (T4) + setprio (T5) + XCD swizzle (T1).
template <int MODE>
__global__ __launch_bounds__(256) void gemm_k(
    const short* Ab, const short* Wt, const float* b0, const float* b1,
    const float* b2, short* Qp, short* Kp, short* Vpt, float* outF) {
  constexpr int BN = (MODE == 0) ? 128 : 64;
  constexpr int NT = BN / 32;          // per-wave n-frags (4 or 2)
  __shared__ short As[2][128 * 32];
  __shared__ short Bs[2][BN * 32];
  int tid = threadIdx.x, lane = tid & 63, wave = tid >> 6;
  int g = lane >> 4, c = lane & 15;
  int n0, m0;
  if (MODE == 0) {
    int orig = blockIdx.x + blockIdx.y * 24;   // nwg = 1536 (%8==0)
    int wg = (orig & 7) * 192 + (orig >> 3);
    n0 = (wg % 24) * 128; m0 = (wg / 24) * 128;
  } else {
    int orig = blockIdx.x + blockIdx.y * 16;   // nwg = 1024
    int wg = (orig & 7) * 128 + (orig >> 3);
    n0 = (wg & 15) * 64; m0 = (wg >> 4) * 128;
  }
  int seg = n0 >> 10;                   // MODE0: 0=Q 1=K 2=V
  const short* Az = (MODE == 0) ? Ab + (size_t)seg * 8388608 : Ab;
  const short* Wz = Wt;                 // Wt is [n_global][k] for n in [0,3072)
  const float* bias = (MODE == 0) ? (seg == 0 ? b0 : (seg == 1 ? b1 : b2)) : b0;

  auto stage = [&](int ks, int buf) {
    const char* ga = (const char*)Az + ((size_t)m0 * 1024 + ks * 32) * 2;
    const char* gb = (const char*)Wz + ((size_t)n0 * 1024 + ks * 32) * 2;
#pragma unroll
    for (int i = 0; i < 2; ++i) {
      int ch = i * 256 + tid;
      int row = ch >> 2, slot = ch & 3;
      int sw = ((row >> 1) & 3) << 4;
      char* dstA = (char*)&As[buf][0] + (i * 256 + wave * 64) * 16;
      async16(ga + (size_t)row * 2048 + ((slot << 4) ^ sw), dstA);
    }
#pragma unroll
    for (int i = 0; i < BN / 64; ++i) {
      int ch = i * 256 + tid;
      int row = ch >> 2, slot = ch & 3;
      int sw = ((row >> 1) & 3) << 4;
      char* dstB = (char*)&Bs[buf][0] + (i * 256 + wave * 64) * 16;
      async16(gb + (size_t)row * 2048 + ((slot << 4) ^ sw), dstB);
    }
  };

  f32x4 acc[4][NT];
#pragma unroll
  for (int i = 0; i < 4; ++i)
#pragma unroll
    for (int j = 0; j < NT; ++j) acc[i][j] = (f32x4){0.f, 0.f, 0.f, 0.f};

  int wr = (wave >> 1) * 64, wc = (wave & 1) * (BN / 2);

  stage(0, 0);
  for (int ks = 0; ks < 32; ++ks) {
    if (ks + 1 < 32) {
      stage(ks + 1, (ks & 1) ^ 1);
      if (MODE == 0) { VM_WAIT4; } else { VM_WAIT3; }
    } else {
      VM_WAIT0;
    }
    __builtin_amdgcn_s_barrier();      // all waves' stage(ks) landed
    int cur = ks & 1;
    bf16x8 af[4], bfv[NT];
#pragma unroll
    for (int mt = 0; mt < 4; ++mt) {
      int r_ = wr + mt * 16 + c;
      af[mt] = *(const bf16x8*)((const char*)&As[cur][0] + r_ * 64 +
                                ((g << 4) ^ ((((r_ >> 1) & 3)) << 4)));
    }
#pragma unroll
    for (int nt = 0; nt < NT; ++nt) {
      int r_ = wc + nt * 16 + c;
      bfv[nt] = *(const bf16x8*)((const char*)&Bs[cur][0] + r_ * 64 +
                                 ((g << 4) ^ ((((r_ >> 1) & 3)) << 4)));
    }
    __builtin_amdgcn_s_setprio(1);
#pragma unroll
    for (int mt = 0; mt < 4; ++mt)
#pragma unroll
      for (int nt = 0; nt < NT; ++nt)
        acc[mt][nt] = __builtin_amdgcn_mfma_f32_16x16x32_bf16(bfv[nt], af[mt], acc[mt][nt], 0, 0, 0);
    __builtin_amdgcn_s_setprio(0);
    __builtin_amdgcn_s_barrier();      // reads of buf[cur] done -> next stage may overwrite
  }

  // Epilogues. C^T fragments: acc[mt][nt][r] = C[m][n = nb + r].
  if (MODE == 0) {
    float scale = (seg == 0) ? 0.125f : 1.f;
#pragma unroll
    for (int nt = 0; nt < NT; ++nt) {
      int nb = n0 + wc + nt * 16 + g * 4;         // global n, r spans nb..nb+3
      float4 b4 = *(const float4*)(bias + (nb & 1023));
      float bb[4] = {b4.x, b4.y, b4.z, b4.w};
      int d0 = nb & 63, nh = (nb >> 6) & 15;
      if (seg < 2) {
        short* dst0 = (seg == 0) ? Qp : Kp;
#pragma unroll
        for (int mt = 0; mt < 4; ++mt) {
          int m = m0 + wr + mt * 16 + c;
          int bh = (m >> 11) * 16 + nh;
          short4 hv;
          hv.x = f2bf((acc[mt][nt][0] + bb[0]) * scale);
          hv.y = f2bf((acc[mt][nt][1] + bb[1]) * scale);
          hv.z = f2bf((acc[mt][nt][2] + bb[2]) * scale);
          hv.w = f2bf((acc[mt][nt][3] + bb[3]) * scale);
          *(short4*)(dst0 + ((size_t)bh * 2048 + (m & 2047)) * 64 + d0) = hv;
        }
      } else {
        // V -> Vpt (bh, d, s): scalar stores, lanes contiguous in s (c)
#pragma unroll
        for (int mt = 0; mt < 4; ++mt) {
          int m = m0 + wr + mt * 16 + c;
          int s = m & 2047, bh = (m >> 11) * 16 + nh;
#pragma unroll
          for (int r = 0; r < 4; ++r)
            Vpt[((size_t)bh * 64 + d0 + r) * 2048 + s] = f2bf(acc[mt][nt][r] + bb[r]);
        }
      }
    }
  } else {
#pragma unroll
    for (int nt = 0; nt < NT; ++nt) {
      int nb = n0 + wc + nt * 16 + g * 4;
      float4 b4 = *(const float4*)(bias + nb);
#pragma unroll
      for (int mt = 0; mt < 4; ++mt) {
        int m = m0 + wr + mt * 16 + c;
        float4 o;
        o.x = acc[mt][nt][0] + b4.x;
        o.y = acc[mt][nt][1] + b4.y;
        o.z = acc[mt][nt][2] + b4.z;
        o.w = acc[mt][nt][3] + b4.w;
        *(float4*)(outF + (size_t)m * 1024 + nb) = o;
      }
    }
  }
}

// ---------------------------------------------------------------------------
// Flash attention, SWAPPED operands: S^T = mfma(K,Q), kv axis lane-local.
// Counted-vmcnt 2-barrier pipeline; Ps aliases Qs (40KB -> 4 blocks/CU);
// XCD swizzle; softmax on packed f32x2 (v_pk_add/mul_f32).
__global__ __launch_bounds__(256) void attn_k(const short* Qp, const short* Kp,
                                              const short* Vpt, const float* mask,
                                              float* outW, short* wbf) {
  __shared__ short Qs[64 * 64];        // prologue: Q tile; loop: P tile (alias)
  __shared__ short Ks[2][64 * 64];
  __shared__ short Vs[2][64 * 64];
  short* Ps = Qs;
  int tid = threadIdx.x, lane = tid & 63, wave = tid >> 6;
  int g = lane >> 4, c = lane & 15;
  int orig = blockIdx.x + blockIdx.y * 32;   // nwg = 2048
  int wg = (orig & 7) * 256 + (orig >> 3);
  int qt = wg & 31, bh = wg >> 5;
  int b = bh >> 4, h = bh & 15;

  const char* Qg = (const char*)Qp + ((size_t)bh * 2048 + qt * 64) * 128;
  const char* Kg = (const char*)Kp + (size_t)bh * 2048 * 128;
  const char* Vg = (const char*)Vpt + (size_t)bh * 64 * 4096;

  stage8k(Qg, 128, Qs, tid);           // issued FIRST (oldest in vmcnt order)
  stage8k(Kg, 128, Ks[0], tid);
  stage8k(Vg, 4096, Vs[0], tid);

  f32x4 acco[4];
#pragma unroll
  for (int i = 0; i < 4; ++i) acco[i] = (f32x4){0.f, 0.f, 0.f, 0.f};
  float mrun = -1e30f, lrun = 0.f;

  VM_WAIT4;  // waits the 2 oldest (= own Q rows; aq rows are wave-local)
  int qrow = wave * 16 + c;            // this lane's q row (col index in S^T)
  bf16x8 aq[2];
#pragma unroll
  for (int k2 = 0; k2 < 2; ++k2)
    aq[k2] = *(const bf16x8*)((const char*)Qs + qrow * 128 +
                              ((k2 * 64 + g * 16) ^ ((qrow & 7) << 4)));

  int cur = 0;
  for (int t = 0; t < 32; ++t) {
    // mask loads FIRST (so vmcnt(4) below never drains the new stage)
    float4 mk[4];
#pragma unroll
    for (int n = 0; n < 4; ++n)
      mk[n] = *(const float4*)(mask + (size_t)b * 2048 + t * 64 + n * 16 + g * 4);
    __builtin_amdgcn_sched_barrier(0);
    if (t + 1 < 32) {
      stage8k(Kg + (size_t)(t + 1) * 8192, 128, Ks[cur ^ 1], tid);
      stage8k(Vg + (size_t)(t + 1) * 128, 4096, Vs[cur ^ 1], tid);
    }
    VM_WAIT4;                          // own stage(t) + mask landed; stage(t+1) in flight
    __builtin_amdgcn_s_barrier();      // all waves' stage(t) landed
    // ---- S^T[kv][q]: A=K rows(kv), B=Q cols(q) ----
    f32x4 sc[4];
    __builtin_amdgcn_s_setprio(1);
#pragma unroll
    for (int n = 0; n < 4; ++n) {
      sc[n] = (f32x4){0.f, 0.f, 0.f, 0.f};
#pragma unroll
      for (int k2 = 0; k2 < 2; ++k2) {
        int row = n * 16 + c;
        bf16x8 bk = *(const bf16x8*)((const char*)&Ks[cur][0] + row * 128 +
                                     ((k2 * 64 + g * 16) ^ ((row & 7) << 4)));
        sc[n] = __builtin_amdgcn_mfma_f32_16x16x32_bf16(bk, aq[k2], sc[n], 0, 0, 0);
      }
    }
    __builtin_amdgcn_s_setprio(0);
    // ---- mask + online softmax along kv, packed f32x2 ----
    f32x2 sv[8];
#pragma unroll
    for (int n = 0; n < 4; ++n) {
      f32x2 mlo = {mk[n].x, mk[n].y}, mhi = {mk[n].z, mk[n].w};
      sv[2 * n]     = __builtin_shufflevector(sc[n], sc[n], 0, 1) + mlo;
      sv[2 * n + 1] = __builtin_shufflevector(sc[n], sc[n], 2, 3) + mhi;
    }
    float tmax = fmaxf(sv[0][0], sv[0][1]);
#pragma unroll
    for (int i = 1; i < 8; ++i) tmax = fmaxf(tmax, fmaxf(sv[i][0], sv[i][1]));
    tmax = fmaxf(tmax, __shfl_xor(tmax, 16));
    tmax = fmaxf(tmax, __shfl_xor(tmax, 32));
    if (!__all(tmax <= mrun + 8.0f)) {   // defer-max (T13)
      float mnew = fmaxf(mrun, tmax);
      float fsc = __expf(mrun - mnew);
      mrun = mnew;
      lrun *= fsc;
#pragma unroll
      for (int n = 0; n < 4; ++n) acco[n] *= fsc;
    }
    f32x2 mr2 = {mrun, mrun};
    f32x2 rs2 = {0.f, 0.f};
    f32x2 p2[8];
#pragma unroll
    for (int i = 0; i < 8; ++i) {
      f32x2 e = sv[i] - mr2;
      f32x2 pe = {__expf(e[0]), __expf(e[1])};
      p2[i] = pe;
      rs2 += pe;
    }
    float rs = rs2[0] + rs2[1];
    rs += __shfl_xor(rs, 16);
    rs += __shfl_xor(rs, 32);
    lrun += rs;
    // ---- P -> LDS [q][kv] (wave-local rows; Ps aliases Qs) ----
#pragma unroll
    for (int n = 0; n < 4; ++n) {
      short4 hv;
      hv.x = f2bf(p2[2 * n][0]);     hv.y = f2bf(p2[2 * n][1]);
      hv.z = f2bf(p2[2 * n + 1][0]); hv.w = f2bf(p2[2 * n + 1][1]);
      int colb = (n * 32 + g * 8) ^ ((qrow & 7) << 4);
      *(short4*)((char*)Ps + qrow * 128 + colb) = hv;
    }
    // ---- O^T += V^T P : A=V^T rows(d), B=P cols(q) ----
    __builtin_amdgcn_s_setprio(1);
#pragma unroll
    for (int k2 = 0; k2 < 2; ++k2) {
      bf16x8 ap = *(const bf16x8*)((const char*)Ps + qrow * 128 +
                                   ((k2 * 64 + g * 16) ^ ((qrow & 7) << 4)));
#pragma unroll
      for (int n2 = 0; n2 < 4; ++n2) {
        int rv = n2 * 16 + c;
        bf16x8 bv = *(const bf16x8*)((const char*)&Vs[cur][0] + rv * 128 +
                                     ((k2 * 64 + g * 16) ^ ((rv & 7) << 4)));
        acco[n2] = __builtin_amdgcn_mfma_f32_16x16x32_bf16(bv, ap, acco[n2], 0, 0, 0);
      }
    }
    __builtin_amdgcn_s_setprio(0);
    __builtin_amdgcn_s_barrier();      // reads of buf[cur] done -> next stage safe
    cur ^= 1;
  }
  // ---- epilogue: O^T[d][q] / l -> float4 along d ----
  float inv = 1.0f / lrun;
  int srow = qt * 64 + qrow;
#pragma unroll
  for (int n = 0; n < 4; ++n) {
    int col0 = h * 64 + n * 16 + g * 4;
    size_t idx = ((size_t)b * 2048 + srow) * 1024 + col0;
    f32x4 o4 = acco[n] * inv;
    float4 o = {o4[0], o4[1], o4[2], o4[3]};
    *(float4*)(outW + idx) = o;
    short4 hv;
    hv.x = f2bf(o.x); hv.y = f2bf(o.y); hv.z = f2bf(o.z); hv.w = f2bf(o.w);
    *(short4*)(wbf + idx) = hv;
  }
}

// ---------------------------------------------------------------------------
extern "C" void kernel_launch(void* const* d_in, const int* in_sizes, int n_in,
                              void* d_out, int out_size, void* d_ws, size_t ws_size,
                              hipStream_t stream) {
  const float* q    = (const float*)d_in[0];
  const float* k    = (const float*)d_in[1];
  const float* v    = (const float*)d_in[2];
  const float* mask = (const float*)d_in[3];
  const float* Wq   = (const float*)d_in[4];
  const float* bq   = (const float*)d_in[5];
  const float* Wk   = (const float*)d_in[6];
  const float* bk   = (const float*)d_in[7];
  const float* Wv   = (const float*)d_in[8];
  const float* bv   = (const float*)d_in[9];
  const float* Wo   = (const float*)d_in[10];
  const float* bo   = (const float*)d_in[11];

  // ws (shorts, 72 MiB): Wt[4M] | Qp[8M] | Kp[8M] | Vpt[8M] | Wbf[8M]
  short* Wt  = (short*)d_ws;
  short* Qp  = Wt + (size_t)4 * 1048576;
  short* Kp  = Qp + (size_t)8388608;
  short* Vpt = Kp + (size_t)8388608;
  short* Wbf = Vpt + (size_t)8388608;

  float* out1 = (float*)d_out;            // (B,S,1024) final output
  float* out2 = out1 + (size_t)8388608;   // (B,S,H*DV) attention weights

  // Abf (bf16 activations, 48 MB) lives in d_out — dead before out1/out2 are
  // written: cvta fills d_out[0,48MB); QKV GEMM consumes it; attn then writes
  // out2 [32,64MB); gemm<2> finally writes out1 [0,32MB).
  short* Abf = (short*)d_out;

  cvtw_k<<<dim3(16, 16, 4), dim3(256), 0, stream>>>(Wq, Wk, Wv, Wo, Wt);
  cvta_k<<<dim3(4096, 3), dim3(256), 0, stream>>>(q, k, v, Abf);
  gemm_k<0><<<dim3(24, 64), dim3(256), 0, stream>>>(
      Abf, Wt, bq, bk, bv, Qp, Kp, Vpt, (float*)nullptr);
  attn_k<<<dim3(32, 64), dim3(256), 0, stream>>>(Qp, Kp, Vpt, mask, out2, Wbf);
  gemm_k<2><<<dim3(16, 64), dim3(256), 0, stream>>>(
      Wbf, Wt + (size_t)3 * 1048576, bo, (const float*)nullptr, (const float*)nullptr,
      (short*)nullptr, (short*)nullptr, (short*)nullptr, out1);
}